// Round 4
// baseline (4499.211 us; speedup 1.0000x reference)
//
#include <hip/hip_runtime.h>
#include <stdint.h>

#define NB 512
#define NT 64
#define NF 128
#define NU 1024
#define NG 4096
#define NS 32

typedef __attribute__((ext_vector_type(8))) short short8;
typedef __attribute__((ext_vector_type(4))) float f32x4;
typedef __attribute__((ext_vector_type(4))) unsigned int u32x4;

__device__ __forceinline__ float sigm(float x) { return 1.0f / (1.0f + __expf(-x)); }
__device__ __forceinline__ float tanh_f(float x) {
  float ax = fabsf(x);
  float e = __expf(2.0f * ax);        // e >= 1; inf ok
  float t = 1.0f - 2.0f / (e + 1.0f);
  return copysignf(t, x);
}
__device__ __forceinline__ unsigned short f2bf(float f) {
  union { float f; unsigned u; } v; v.f = f;
  unsigned r = v.u + 0x7fffu + ((v.u >> 16) & 1u);  // RNE
  return (unsigned short)(r >> 16);
}

// ---- software grid barrier (all 256 blocks co-resident: 144KB LDS forces 1 block/CU) ----
// Arrive uses RELEASE/AGENT: lowers to buffer_wbl2 sc1 (+waitcnt) on gfx950 -> flushes
// dirty h lines from the producer XCD's L2 into L3 WITHOUT invalidating (weights stay
// L2-resident). Consumers read h with sc0 sc1 bypass loads, so they never hold stale h.
__device__ __forceinline__ void gbar(unsigned* flags, int bid, unsigned gen) {
  __syncthreads();   // drains vmcnt -> all h stores have reached L2
  if (threadIdx.x == 0)
    __hip_atomic_store(flags + bid, gen, __ATOMIC_RELEASE, __HIP_MEMORY_SCOPE_AGENT);
  if (bid == 0) {
    if (threadIdx.x < 256) {
      while (__hip_atomic_load(flags + threadIdx.x, __ATOMIC_RELAXED, __HIP_MEMORY_SCOPE_AGENT) != gen)
        __builtin_amdgcn_s_sleep(1);
    }
    __syncthreads();
    if (threadIdx.x == 0)
      __hip_atomic_store(flags + 256, gen, __ATOMIC_RELAXED, __HIP_MEMORY_SCOPE_AGENT);
  } else if (threadIdx.x == 0) {
    while (__hip_atomic_load(flags + 256, __ATOMIC_RELAXED, __HIP_MEMORY_SCOPE_AGENT) != gen)
      __builtin_amdgcn_s_sleep(1);
  }
  __syncthreads();
}

// ---------------- one fused LSTM step (device function) ----------------
// Tile: 64 rows x 32 units x 4 gates per block. 8 waves = kh(4: K quarters) x wu(2: 16 units).
// Each wave: 4 row-tiles x 16 units x 4 gates over K/4 -> acc[4][4] f32x4.
// B traffic/block = 256KB (waves own disjoint B), A(h) staged once in LDS (128KB).
template <int KX>
__device__ __forceinline__ void do_step(
    const unsigned short* __restrict__ hIn,   // [512][1024] bf16 (read via sc0 sc1)
    const unsigned short* __restrict__ Bp,    // packed [128][4096][8] bf16
    const unsigned short* __restrict__ Xp,    // [64][512][128] bf16 or null
    const unsigned short* __restrict__ W1p,   // packed [16][4096][8] bf16 or null
    int tstep, f32x4 bA, f32x4 (&cst)[4],
    unsigned short* __restrict__ hOut, unsigned short* __restrict__ hOut2,
    unsigned short* lds,
    int r0, int u0, int kh, int wu, int lr, int g4, int ucol, int tid)
{
  constexpr int ROWB = (NU + KX) * 2;         // LDS row bytes

  // ---- stage A (64 h rows) into LDS, XOR-swizzled; bypass loads read L3 ----
  {
    u32x4 t[16];
    const unsigned short* src[16];
    int loff[16];
#pragma unroll
    for (int it = 0; it < 16; ++it) {
      int i = tid + it * 512;
      int r = i >> 7, cb = i & 127;
      src[it] = hIn + (size_t)(r0 + r) * NU + cb * 8;
      loff[it] = r * ROWB + ((cb * 16) ^ ((r & 7) << 4));
    }
#pragma unroll
    for (int it = 0; it < 16; ++it)
      asm volatile("global_load_dwordx4 %0, %1, off sc0 sc1" : "=v"(t[it]) : "v"(src[it]));
    if constexpr (KX > 0) {
      u32x4 vx[2]; int ox[2];
#pragma unroll
      for (int it = 0; it < 2; ++it) {
        int i = tid + it * 512;                 // 64 rows x 16 chunks
        int r = i >> 4, cb = i & 15;
        vx[it] = *(const u32x4*)(Xp + ((size_t)tstep * NB + (r0 + r)) * NF + cb * 8);
        ox[it] = r * ROWB + ((NU * 2 + cb * 16) ^ ((r & 7) << 4));
      }
      asm volatile("s_waitcnt vmcnt(0)" ::: "memory");
      __builtin_amdgcn_sched_barrier(0);
#pragma unroll
      for (int it = 0; it < 16; ++it) *(u32x4*)((char*)lds + loff[it]) = t[it];
#pragma unroll
      for (int it = 0; it < 2; ++it) *(u32x4*)((char*)lds + ox[it]) = vx[it];
    } else {
      asm volatile("s_waitcnt vmcnt(0)" ::: "memory");
      __builtin_amdgcn_sched_barrier(0);
#pragma unroll
      for (int it = 0; it < 16; ++it) *(u32x4*)((char*)lds + loff[it]) = t[it];
    }
  }
  __syncthreads();

  f32x4 acc[4][4];   // [gate][row-tile]
#pragma unroll
  for (int g = 0; g < 4; ++g)
#pragma unroll
    for (int rt = 0; rt < 4; ++rt) acc[g][rt] = (f32x4){0.f, 0.f, 0.f, 0.f};

  const char* ldsb = (const char*)lds;
  int arow[4];
#pragma unroll
  for (int rt = 0; rt < 4; ++rt) arow[rt] = (rt * 16 + lr) * ROWB;
  const int axor = (lr & 7) << 4;
  const int kcb = kh * 8;                      // this wave's K quarter (8 chunks of 32)

  // 2-deep B prefetch
  short8 nb[2][4];
#pragma unroll
  for (int p = 0; p < 2; ++p) {
    size_t base = ((size_t)((kcb + p) * 4 + g4) * NG + ucol) * 8;
#pragma unroll
    for (int g = 0; g < 4; ++g) nb[p][g] = *(const short8*)(Bp + base + (size_t)g * NU * 8);
  }
#pragma unroll
  for (int kc = 0; kc < 8; ++kc) {
    short8 bb[4];
#pragma unroll
    for (int g = 0; g < 4; ++g) bb[g] = nb[kc & 1][g];
    if (kc < 6) {
      size_t base = ((size_t)((kcb + kc + 2) * 4 + g4) * NG + ucol) * 8;
#pragma unroll
      for (int g = 0; g < 4; ++g) nb[kc & 1][g] = *(const short8*)(Bp + base + (size_t)g * NU * 8);
    }
    int kb = ((kcb + kc) * 64 + g4 * 16) ^ axor;
    short8 a[4];
#pragma unroll
    for (int rt = 0; rt < 4; ++rt) a[rt] = *(const short8*)(ldsb + arow[rt] + kb);
#pragma unroll
    for (int g = 0; g < 4; ++g)
#pragma unroll
      for (int rt = 0; rt < 4; ++rt)
        acc[g][rt] = __builtin_amdgcn_mfma_f32_16x16x32_bf16(a[rt], bb[g], acc[g][rt], 0, 0, 0);
  }
  if constexpr (KX > 0) {                      // x-part: each kh owns one 32-K chunk
    int kb = (NU * 2 + kh * 64 + g4 * 16) ^ axor;
    size_t base = ((size_t)(kh * 4 + g4) * NG + ucol) * 8;
    short8 bb[4];
#pragma unroll
    for (int g = 0; g < 4; ++g) bb[g] = *(const short8*)(W1p + base + (size_t)g * NU * 8);
    short8 a[4];
#pragma unroll
    for (int rt = 0; rt < 4; ++rt) a[rt] = *(const short8*)(ldsb + arow[rt] + kb);
#pragma unroll
    for (int g = 0; g < 4; ++g)
#pragma unroll
      for (int rt = 0; rt < 4; ++rt)
        acc[g][rt] = __builtin_amdgcn_mfma_f32_16x16x32_bf16(a[rt], bb[g], acc[g][rt], 0, 0, 0);
  }

  // ---- 4-way K-split reduction via LDS (A-region reused; 6 slots x 16KB = 96KB) ----
  __syncthreads();
  const int l = (g4 << 4) | lr;
  float* red = (float*)lds;
  if (kh != 0) {
    float* base = red + (size_t)((kh - 1) * 2 + wu) * 4096;
#pragma unroll
    for (int g = 0; g < 4; ++g)
#pragma unroll
      for (int rt = 0; rt < 4; ++rt)
        *(f32x4*)(base + ((g * 4 + rt) * 64 + l) * 4) = acc[g][rt];
  }
  __syncthreads();
  if (kh == 0) {
#pragma unroll
    for (int s = 0; s < 3; ++s) {
      float* base = red + (size_t)(s * 2 + wu) * 4096;
#pragma unroll
      for (int g = 0; g < 4; ++g)
#pragma unroll
        for (int rt = 0; rt < 4; ++rt)
          acc[g][rt] += *(const f32x4*)(base + ((g * 4 + rt) * 64 + l) * 4);
    }
    // ---- epilogue: gates + c update in registers; h via NORMAL cached stores ----
#pragma unroll
    for (int rt = 0; rt < 4; ++rt) {
#pragma unroll
      for (int j = 0; j < 4; ++j) {
        int r = r0 + rt * 16 + g4 * 4 + j;     // C/D: row=(lane>>4)*4+j, col=lane&15
        size_t idx = (size_t)r * NU + ucol;
        float iv = sigm(acc[0][rt][j] + bA[0]);
        float fv = sigm(acc[1][rt][j] + bA[1]);
        float gv = tanh_f(acc[2][rt][j] + bA[2]);
        float ov = sigm(acc[3][rt][j] + bA[3]);
        float cN = fv * cst[rt][j] + iv * gv;
        cst[rt][j] = cN;
        unsigned short hv = f2bf(ov * tanh_f(cN));
        hOut[idx] = hv;
        if (hOut2) hOut2[idx] = hv;
      }
    }
  }
}

// ---------------- persistent kernel: whole 126-step serial chain ----------------
__global__ __launch_bounds__(512, 1) void lstm_seq(
    const unsigned short* __restrict__ U1p, const unsigned short* __restrict__ U1pp,
    const unsigned short* __restrict__ W2U2p, const unsigned short* __restrict__ W1p,
    const unsigned short* __restrict__ x2,
    const float* __restrict__ b1, const float* __restrict__ b1p, const float* __restrict__ b2,
    unsigned short* __restrict__ h0, unsigned short* __restrict__ h1,
    unsigned short* __restrict__ hist, unsigned* __restrict__ flags)
{
  extern __shared__ unsigned short lds[];
  const int bid = blockIdx.x;
  const int xcd = bid & 7, slot = bid >> 3;   // per-XCD B slice = 4 u_blks = 1MB, L2-resident
  const int u_blk = xcd * 4 + (slot >> 3);    // 0..31
  const int m_blk = slot & 7;                 // 0..7
  const int r0 = m_blk * 64, u0 = u_blk * 32;
  const int tid = threadIdx.x;
  const int w = tid >> 6, kh = w >> 1, wu = w & 1;
  const int lr = tid & 15, g4 = (tid >> 4) & 3;
  const int ucol = u0 + wu * 16 + lr;
  const size_t HS = (size_t)NB * NU;

  f32x4 bW, bC1, bC2;
#pragma unroll
  for (int g = 0; g < 4; ++g) {
    bW[g]  = b1 [g * NU + ucol];
    bC1[g] = b1p[g * NU + ucol];
    bC2[g] = b2 [g * NU + ucol];
  }
  f32x4 cst[4];
#pragma unroll
  for (int rt = 0; rt < 4; ++rt) cst[rt] = (f32x4){0.f, 0.f, 0.f, 0.f};

  unsigned gen = 0;
  // warmup: h0 (zeroed) <-> h1; final h lands in h0-slot (also hist[0])
  for (int t = 0; t < NT; ++t) {
    const unsigned short* hi = (t & 1) ? h1 : h0;
    unsigned short* ho = (t & 1) ? h0 : h1;
    do_step<NF>(hi, U1p, x2, W1p, t, bW, cst, ho, (t == NT - 1) ? hist : nullptr,
                lds, r0, u0, kh, wu, lr, g4, ucol, tid);
    gbar(flags, bid, ++gen);
  }
  // AR: cell1 (U1'=Wd@W1+U1): h0->h1 ; cell2 (W2+U2): h1->h0 (+hist[s+1])
  for (int s = 0; s < NS - 1; ++s) {
    do_step<0>(h0, U1pp, nullptr, nullptr, 0, bC1, cst, h1, nullptr,
               lds, r0, u0, kh, wu, lr, g4, ucol, tid);
    gbar(flags, bid, ++gen);
    do_step<0>(h1, W2U2p, nullptr, nullptr, 0, bC2, cst, h0, hist + (size_t)(s + 1) * HS,
               lds, r0, u0, kh, wu, lr, g4, ucol, tid);
    if (s < NS - 2) gbar(flags, bid, ++gen);
  }
}

// ---------------- batched output projection: out[b][s][f] = hist[s][b]@Wd + bd ----------------
__global__ __launch_bounds__(256, 2) void pred_gemm(
    const unsigned short* __restrict__ H,    // [32*512][1024] bf16
    const unsigned short* __restrict__ Wdp,  // packed [128][128][8] bf16
    const float* __restrict__ bd, float* __restrict__ out)
{
  __shared__ unsigned short lds[32 * NU];
  const int tid = threadIdx.x;
  const int r0 = blockIdx.x * 32;
  for (int i = tid; i < 32 * 128; i += 256) {
    int r = i >> 7, cb = i & 127;
    uint4 v = *(const uint4*)(H + (size_t)(r0 + r) * NU + cb * 8);
    int off = r * 2048 + ((cb * 16) ^ ((r & 7) << 4));
    *(uint4*)((char*)lds + off) = v;
  }
  __syncthreads();
  const int w = tid >> 6, l = tid & 63, lr = l & 15, g4 = l >> 4;
  f32x4 acc[2][2];
#pragma unroll
  for (int a = 0; a < 2; ++a)
#pragma unroll
    for (int c = 0; c < 2; ++c) acc[a][c] = (f32x4){0.f, 0.f, 0.f, 0.f};
  const char* ldsb = (const char*)lds;
  const int arow0 = lr * 2048, arow1 = (16 + lr) * 2048, axor = (lr & 7) << 4;
  const int col0 = w * 32 + lr;
#pragma unroll 4
  for (int kc = 0; kc < 32; ++kc) {
    int kb = (kc * 64 + g4 * 16) ^ axor;
    short8 a0 = *(const short8*)(ldsb + arow0 + kb);
    short8 a1 = *(const short8*)(ldsb + arow1 + kb);
    size_t base = ((size_t)(kc * 4 + g4) * NF) * 8;
    short8 w0 = *(const short8*)(Wdp + base + (size_t)col0 * 8);
    short8 w1 = *(const short8*)(Wdp + base + (size_t)(col0 + 16) * 8);
    acc[0][0] = __builtin_amdgcn_mfma_f32_16x16x32_bf16(a0, w0, acc[0][0], 0, 0, 0);
    acc[1][0] = __builtin_amdgcn_mfma_f32_16x16x32_bf16(a1, w0, acc[1][0], 0, 0, 0);
    acc[0][1] = __builtin_amdgcn_mfma_f32_16x16x32_bf16(a0, w1, acc[0][1], 0, 0, 0);
    acc[1][1] = __builtin_amdgcn_mfma_f32_16x16x32_bf16(a1, w1, acc[1][1], 0, 0, 0);
  }
#pragma unroll
  for (int rt = 0; rt < 2; ++rt)
#pragma unroll
    for (int ct = 0; ct < 2; ++ct)
#pragma unroll
      for (int j = 0; j < 4; ++j) {
        int r = r0 + rt * 16 + g4 * 4 + j;
        int s = r >> 9, bb = r & 511;
        int f = w * 32 + ct * 16 + lr;
        out[((size_t)bb * NS + s) * NF + f] = acc[rt][ct][j] + bd[f];
      }
}

// ---------------- prep kernels ----------------
// x2 in [T][B][F] layout (contiguous per-step staging)
__global__ void prep_x(const float* __restrict__ in, const float* __restrict__ mean,
                       const float* __restrict__ var, unsigned short* __restrict__ x2) {
  int i = (blockIdx.x * 256 + threadIdx.x) * 4;
  int f = i & 127;
  int bt = i >> 7;
  int b = bt >> 6, t = bt & 63;
  float4 v = *(const float4*)(in + i);
  float vv[4] = {v.x, v.y, v.z, v.w};
  unsigned short o[4] __attribute__((aligned(8)));
#pragma unroll
  for (int j = 0; j < 4; ++j) {
    float inv = rsqrtf(var[f + j] + 1e-7f);
    float s = inv * inv;
    float m2 = mean[f + j] * (s + inv);   // double-normalization folded
    o[j] = f2bf(vv[j] * s - m2);
  }
  *(uint2*)(x2 + (((size_t)t * NB + b) << 7) + f) = *(const uint2*)o;
}

// P[(k/8)*N*8 + c*8 + k%8] = bf16(A[k][c] (+ A2[k][c]))
__global__ void prep_pack(const float* __restrict__ A, const float* __restrict__ A2,
                          unsigned short* __restrict__ P, int N) {
  int idx = blockIdx.x * 256 + threadIdx.x;
  int kg = idx / N, c = idx - kg * N;
  unsigned short o[8] __attribute__((aligned(16)));
#pragma unroll
  for (int j = 0; j < 8; ++j) {
    size_t e = (size_t)(kg * 8 + j) * N + c;
    float vv = A[e];
    if (A2) vv += A2[e];
    o[j] = f2bf(vv);
  }
  *(uint4*)(P + (size_t)idx * 8) = *(const uint4*)o;
}

// U1' = U1 + Wd@W1, packed.  Wd slice staged in LDS; m-loop unrolled.
__global__ __launch_bounds__(256) void prep_u1pp(
    const float* __restrict__ U1, const float* __restrict__ Wd,
    const float* __restrict__ W1, unsigned short* __restrict__ P) {
  __shared__ float wd[8][NF];
  const int kg = blockIdx.x >> 4;
  const int c = ((blockIdx.x & 15) << 8) + threadIdx.x;
  for (int i = threadIdx.x; i < 8 * NF; i += 256)
    wd[i >> 7][i & 127] = Wd[(size_t)(kg * 8 + (i >> 7)) * NF + (i & 127)];
  __syncthreads();
  float a[8];
#pragma unroll
  for (int j = 0; j < 8; ++j) a[j] = U1[(size_t)(kg * 8 + j) * NG + c];
#pragma unroll 8
  for (int m = 0; m < NF; ++m) {
    float w1v = W1[(size_t)m * NG + c];
#pragma unroll
    for (int j = 0; j < 8; ++j) a[j] += wd[j][m] * w1v;
  }
  unsigned short o[8] __attribute__((aligned(16)));
#pragma unroll
  for (int j = 0; j < 8; ++j) o[j] = f2bf(a[j]);
  *(uint4*)(P + (size_t)(kg * NG + c) * 8) = *(const uint4*)o;
}

__global__ void prep_wdp(const float* __restrict__ Wd, unsigned short* __restrict__ P) {
  int idx = blockIdx.x * 256 + threadIdx.x;  // kg*128 + f
  int kg = idx >> 7, f = idx & 127;
  unsigned short o[8] __attribute__((aligned(16)));
#pragma unroll
  for (int j = 0; j < 8; ++j) o[j] = f2bf(Wd[(size_t)(kg * 8 + j) * NF + f]);
  *(uint4*)(P + (size_t)idx * 8) = *(const uint4*)o;
}

// b1' = b1 + bd@W1
__global__ void prep_b1p(const float* __restrict__ b1, const float* __restrict__ bd,
                         const float* __restrict__ W1, float* __restrict__ o) {
  int c = blockIdx.x * 256 + threadIdx.x;
  float acc = b1[c];
#pragma unroll 8
  for (int m = 0; m < NF; ++m) acc += bd[m] * W1[(size_t)m * NG + c];
  o[c] = acc;
}

extern "C" void kernel_launch(void* const* d_in, const int* in_sizes, int n_in,
                              void* d_out, int out_size, void* d_ws, size_t ws_size,
                              hipStream_t stream) {
  const float* inputs = (const float*)d_in[0];
  const float* mean = (const float*)d_in[1];
  const float* var  = (const float*)d_in[2];
  const float* W1   = (const float*)d_in[3];
  const float* U1   = (const float*)d_in[4];
  const float* b1   = (const float*)d_in[5];
  const float* W2   = (const float*)d_in[6];
  const float* U2   = (const float*)d_in[7];
  const float* b2   = (const float*)d_in[8];
  const float* Wd   = (const float*)d_in[9];
  const float* bd   = (const float*)d_in[10];
  float* out = (float*)d_out;
  char* ws = (char*)d_ws;

  size_t off = 0;
  auto alloc = [&](size_t bytes) { char* p = ws + off; off += (bytes + 255) & ~255ull; return p; };
  unsigned short* h0    = (unsigned short*)alloc((size_t)NB * NU * 2);
  unsigned short* h1    = (unsigned short*)alloc((size_t)NB * NU * 2);
  unsigned short* hist  = (unsigned short*)alloc((size_t)NS * NB * NU * 2);
  unsigned short* x2    = (unsigned short*)alloc((size_t)NB * NT * NF * 2);
  unsigned short* U1p   = (unsigned short*)alloc((size_t)NU * NG * 2);
  unsigned short* U1pp  = (unsigned short*)alloc((size_t)NU * NG * 2);
  unsigned short* W2U2p = (unsigned short*)alloc((size_t)NU * NG * 2);
  unsigned short* W1p   = (unsigned short*)alloc((size_t)NF * NG * 2);
  unsigned short* Wdp   = (unsigned short*)alloc((size_t)NU * NF * 2);
  float* b1p            = (float*)alloc((size_t)NG * 4);
  unsigned* flags       = (unsigned*)alloc(2048);

  hipMemsetAsync(h0, 0, (size_t)NB * NU * 2, stream);
  hipMemsetAsync(flags, 0, 2048, stream);

  prep_x   <<<(NB * NT * NF) / 1024, 256, 0, stream>>>(inputs, mean, var, x2);
  prep_pack<<<(NU / 8) * NG / 256, 256, 0, stream>>>(U1, nullptr, U1p, NG);
  prep_u1pp<<<(NU / 8) * NG / 256, 256, 0, stream>>>(U1, Wd, W1, U1pp);
  prep_pack<<<(NU / 8) * NG / 256, 256, 0, stream>>>(W2, U2, W2U2p, NG);
  prep_pack<<<(NF / 8) * NG / 256, 256, 0, stream>>>(W1, nullptr, W1p, NG);
  prep_wdp <<<(NU / 8) * NF / 256, 256, 0, stream>>>(Wd, Wdp);
  prep_b1p <<<NG / 256, 256, 0, stream>>>(b1, bd, W1, b1p);

  // whole serial chain in one persistent kernel.
  // LDS = 64 rows x (1024+128) cols x 2B = 147456 B -> 1 block/CU -> barrier safe.
  lstm_seq<<<256, 512, 64 * (NU + NF) * 2, stream>>>(U1p, U1pp, W2U2p, W1p, x2,
                                                     b1, b1p, b2, h0, h1, hist, flags);

  // all 32 output projections in one parallel GEMM
  pred_gemm<<<(NS * NB) / 32, 256, 0, stream>>>(hist, Wdp, bd, out);
}

// Round 5
// 2951.678 us; speedup vs baseline: 1.5243x; 1.5243x over previous
//
#include <hip/hip_runtime.h>
#include <stdint.h>

#define NB 512
#define NT 64
#define NF 128
#define NU 1024
#define NG 4096
#define NS 32

typedef __attribute__((ext_vector_type(8))) short short8;
typedef __attribute__((ext_vector_type(4))) float f32x4;
typedef __attribute__((ext_vector_type(4))) unsigned int u32x4;

__device__ __forceinline__ float sigm(float x) { return 1.0f / (1.0f + __expf(-x)); }
__device__ __forceinline__ float tanh_f(float x) {
  float ax = fabsf(x);
  float e = __expf(2.0f * ax);        // e >= 1; inf ok
  float t = 1.0f - 2.0f / (e + 1.0f);
  return copysignf(t, x);
}
__device__ __forceinline__ unsigned short f2bf(float f) {
  union { float f; unsigned u; } v; v.f = f;
  unsigned r = v.u + 0x7fffu + ((v.u >> 16) & 1u);  // RNE
  return (unsigned short)(r >> 16);
}

// R3-proven h-exchange mechanism: write-through (sc0 sc1) stores land in the
// memory-side L3; consumers read with sc0 sc1 bypass loads. No fences, no L2
// invalidation -> weights stay L2-resident. (R4's RELEASE-fence variant blew
// FETCH up 6.5x — do NOT reintroduce cache-maintenance ops in the loop.)
__device__ __forceinline__ void coh_store_bf16(unsigned short* p, unsigned v) {
  asm volatile("global_store_short %0, %1, off sc0 sc1" :: "v"(p), "v"(v) : "memory");
}

// ---- software grid barrier (all 256 blocks co-resident: 144KB LDS forces 1 block/CU) ----
__device__ __forceinline__ void gbar(unsigned* flags, int bid, unsigned gen) {
  __syncthreads();   // compiler drains vmcnt here -> h write-through stores are visible
  if (threadIdx.x == 0)
    __hip_atomic_store(flags + bid, gen, __ATOMIC_RELAXED, __HIP_MEMORY_SCOPE_AGENT);
  if (bid == 0) {
    if (threadIdx.x < 256) {
      while (__hip_atomic_load(flags + threadIdx.x, __ATOMIC_RELAXED, __HIP_MEMORY_SCOPE_AGENT) != gen)
        __builtin_amdgcn_s_sleep(1);
    }
    __syncthreads();
    if (threadIdx.x == 0)
      __hip_atomic_store(flags + 256, gen, __ATOMIC_RELAXED, __HIP_MEMORY_SCOPE_AGENT);
  } else if (threadIdx.x == 0) {
    while (__hip_atomic_load(flags + 256, __ATOMIC_RELAXED, __HIP_MEMORY_SCOPE_AGENT) != gen)
      __builtin_amdgcn_s_sleep(1);
  }
  __syncthreads();
}

// ---------------- one fused LSTM step (device function) ----------------
// Tile: 64 rows x 32 units x 4 gates per block. 8 waves = kh(4: K quarters) x wu(2).
// MFMA phase: wave (kh,wu) computes partial z for ALL 4 row-tiles, its 16 units,
//             4 gates, over K/4 (disjoint B slices -> 256KB L2 B-stream per CU).
// Epilogue:   wave (rg=kh,wu) owns rows rg*16..+16 x units wu*16..+16: sums the 4
//             K-slices via LDS (12 wr + 12 rd b128/wave) and applies gates.
//             c-state: 4 floats/thread, lives in registers all 126 steps.
template <int KX>
__device__ __forceinline__ void do_step(
    const unsigned short* __restrict__ hIn,   // [512][1024] bf16 (read via sc0 sc1)
    const unsigned short* __restrict__ Bp,    // packed [128][4096][8] bf16
    const unsigned short* __restrict__ Xp,    // [64][512][128] bf16 or null
    const unsigned short* __restrict__ W1p,   // packed [16][4096][8] bf16 or null
    int tstep, f32x4 bA, f32x4& cst,
    unsigned short* __restrict__ hOut, unsigned short* __restrict__ hOut2,
    unsigned short* lds,
    int r0, int u0, int kh, int wu, int lr, int g4, int ucol, int tid)
{
  constexpr int ROWB = (NU + KX) * 2;         // LDS row bytes
  const int kcb = kh * 8;                     // this wave's K quarter (8 chunks of 32)

  // ---- B 2-deep prefetch issued FIRST: L2 hits complete under the L3 staging wait ----
  short8 nb[2][4];
#pragma unroll
  for (int p = 0; p < 2; ++p) {
    size_t base = ((size_t)((kcb + p) * 4 + g4) * NG + ucol) * 8;
#pragma unroll
    for (int g = 0; g < 4; ++g) nb[p][g] = *(const short8*)(Bp + base + (size_t)g * NU * 8);
  }

  // ---- stage A (64 h rows) into LDS, XOR-swizzled; bypass loads read L3 ----
  {
    u32x4 t[16];
    const unsigned short* src[16];
    int loff[16];
#pragma unroll
    for (int it = 0; it < 16; ++it) {
      int i = tid + it * 512;
      int r = i >> 7, cb = i & 127;
      src[it] = hIn + (size_t)(r0 + r) * NU + cb * 8;
      loff[it] = r * ROWB + ((cb * 16) ^ ((r & 7) << 4));
    }
#pragma unroll
    for (int it = 0; it < 16; ++it)
      asm volatile("global_load_dwordx4 %0, %1, off sc0 sc1" : "=v"(t[it]) : "v"(src[it]));
    if constexpr (KX > 0) {
      u32x4 vx[2]; int ox[2];
#pragma unroll
      for (int it = 0; it < 2; ++it) {
        int i = tid + it * 512;                 // 64 rows x 16 chunks
        int r = i >> 4, cb = i & 15;
        vx[it] = *(const u32x4*)(Xp + ((size_t)tstep * NB + (r0 + r)) * NF + cb * 8);
        ox[it] = r * ROWB + ((NU * 2 + cb * 16) ^ ((r & 7) << 4));
      }
      asm volatile("s_waitcnt vmcnt(0)" ::: "memory");
      __builtin_amdgcn_sched_barrier(0);
#pragma unroll
      for (int it = 0; it < 16; ++it) *(u32x4*)((char*)lds + loff[it]) = t[it];
#pragma unroll
      for (int it = 0; it < 2; ++it) *(u32x4*)((char*)lds + ox[it]) = vx[it];
    } else {
      asm volatile("s_waitcnt vmcnt(0)" ::: "memory");
      __builtin_amdgcn_sched_barrier(0);
#pragma unroll
      for (int it = 0; it < 16; ++it) *(u32x4*)((char*)lds + loff[it]) = t[it];
    }
  }
  __syncthreads();

  f32x4 acc[4][4];   // [gate][row-tile]
#pragma unroll
  for (int g = 0; g < 4; ++g)
#pragma unroll
    for (int rt = 0; rt < 4; ++rt) acc[g][rt] = (f32x4){0.f, 0.f, 0.f, 0.f};

  const char* ldsb = (const char*)lds;
  int arow[4];
#pragma unroll
  for (int rt = 0; rt < 4; ++rt) arow[rt] = (rt * 16 + lr) * ROWB;
  const int axor = (lr & 7) << 4;

#pragma unroll
  for (int kc = 0; kc < 8; ++kc) {
    short8 bb[4];
#pragma unroll
    for (int g = 0; g < 4; ++g) bb[g] = nb[kc & 1][g];
    if (kc < 6) {
      size_t base = ((size_t)((kcb + kc + 2) * 4 + g4) * NG + ucol) * 8;
#pragma unroll
      for (int g = 0; g < 4; ++g) nb[kc & 1][g] = *(const short8*)(Bp + base + (size_t)g * NU * 8);
    }
    int kb = ((kcb + kc) * 64 + g4 * 16) ^ axor;
    short8 a[4];
#pragma unroll
    for (int rt = 0; rt < 4; ++rt) a[rt] = *(const short8*)(ldsb + arow[rt] + kb);
#pragma unroll
    for (int g = 0; g < 4; ++g)
#pragma unroll
      for (int rt = 0; rt < 4; ++rt)
        acc[g][rt] = __builtin_amdgcn_mfma_f32_16x16x32_bf16(a[rt], bb[g], acc[g][rt], 0, 0, 0);
  }
  if constexpr (KX > 0) {                      // x-part: each kh owns one 32-K chunk
    int kb = (NU * 2 + kh * 64 + g4 * 16) ^ axor;
    size_t base = ((size_t)(kh * 4 + g4) * NG + ucol) * 8;
    short8 bb[4];
#pragma unroll
    for (int g = 0; g < 4; ++g) bb[g] = *(const short8*)(W1p + base + (size_t)g * NU * 8);
    short8 a[4];
#pragma unroll
    for (int rt = 0; rt < 4; ++rt) a[rt] = *(const short8*)(ldsb + arow[rt] + kb);
#pragma unroll
    for (int g = 0; g < 4; ++g)
#pragma unroll
      for (int rt = 0; rt < 4; ++rt)
        acc[g][rt] = __builtin_amdgcn_mfma_f32_16x16x32_bf16(a[rt], bb[g], acc[g][rt], 0, 0, 0);
  }

  // ---- all-wave K-reduction via LDS (A-region reused: 8x16 slots x 1KB = 128KB) ----
  // slot[(kh*2+wu)*16 + rt*4 + g] holds one 16x16 f32 tile (64 lanes x f32x4).
  __syncthreads();
  char* redb = (char*)lds;
  const int lane = (g4 << 4) | lr;
#pragma unroll
  for (int rt = 0; rt < 4; ++rt) {
    if (rt == kh) continue;                    // own-slice kept in registers
#pragma unroll
    for (int g = 0; g < 4; ++g)
      *(f32x4*)(redb + ((((kh * 2 + wu) * 16) + rt * 4 + g) << 10) + lane * 16) = acc[g][rt];
  }
  __syncthreads();
  const int rg = kh;                           // epilogue row-tile owned by this wave
  f32x4 z[4];
#pragma unroll
  for (int g = 0; g < 4; ++g) {
    z[g] = acc[g][rg];                         // own K-slice contribution
#pragma unroll
    for (int k2 = 0; k2 < 4; ++k2) {
      if (k2 == rg) continue;
      z[g] += *(const f32x4*)(redb + ((((k2 * 2 + wu) * 16) + rg * 4 + g) << 10) + lane * 16);
    }
  }
  // ---- epilogue: 4 elems/thread on ALL 8 waves; c in registers; h write-through ----
#pragma unroll
  for (int j = 0; j < 4; ++j) {
    int r = r0 + rg * 16 + g4 * 4 + j;         // C/D: row=(lane>>4)*4+j, col=lane&15
    size_t idx = (size_t)r * NU + ucol;
    float iv = sigm(z[0][j] + bA[0]);
    float fv = sigm(z[1][j] + bA[1]);
    float gv = tanh_f(z[2][j] + bA[2]);
    float ov = sigm(z[3][j] + bA[3]);
    float cN = fv * cst[j] + iv * gv;
    cst[j] = cN;
    unsigned hv = f2bf(ov * tanh_f(cN));
    coh_store_bf16(hOut + idx, hv);
    if (hOut2) coh_store_bf16(hOut2 + idx, hv);
  }
}

// ---------------- persistent kernel: whole 126-step serial chain ----------------
__global__ __launch_bounds__(512, 1) void lstm_seq(
    const unsigned short* __restrict__ U1p, const unsigned short* __restrict__ U1pp,
    const unsigned short* __restrict__ W2U2p, const unsigned short* __restrict__ W1p,
    const unsigned short* __restrict__ x2,
    const float* __restrict__ b1, const float* __restrict__ b1p, const float* __restrict__ b2,
    unsigned short* __restrict__ h0, unsigned short* __restrict__ h1,
    unsigned short* __restrict__ hist, unsigned* __restrict__ flags)
{
  extern __shared__ unsigned short lds[];
  const int bid = blockIdx.x;
  const int xcd = bid & 7, slot = bid >> 3;   // per-XCD B slice = 4 u_blks = 1MB, L2-resident
  const int u_blk = xcd * 4 + (slot >> 3);    // 0..31
  const int m_blk = slot & 7;                 // 0..7
  const int r0 = m_blk * 64, u0 = u_blk * 32;
  const int tid = threadIdx.x;
  const int w = tid >> 6, kh = w >> 1, wu = w & 1;
  const int lr = tid & 15, g4 = (tid >> 4) & 3;
  const int ucol = u0 + wu * 16 + lr;
  const size_t HS = (size_t)NB * NU;

  f32x4 bW, bC1, bC2;
#pragma unroll
  for (int g = 0; g < 4; ++g) {
    bW[g]  = b1 [g * NU + ucol];
    bC1[g] = b1p[g * NU + ucol];
    bC2[g] = b2 [g * NU + ucol];
  }
  f32x4 cst = (f32x4){0.f, 0.f, 0.f, 0.f};    // c for rows kh*16+g4*4+j, col ucol

  unsigned gen = 0;
  // warmup: h0 (zeroed) <-> h1; final h lands in h0-slot (also hist[0])
  for (int t = 0; t < NT; ++t) {
    const unsigned short* hi = (t & 1) ? h1 : h0;
    unsigned short* ho = (t & 1) ? h0 : h1;
    do_step<NF>(hi, U1p, x2, W1p, t, bW, cst, ho, (t == NT - 1) ? hist : nullptr,
                lds, r0, u0, kh, wu, lr, g4, ucol, tid);
    gbar(flags, bid, ++gen);
  }
  // AR: cell1 (U1'=Wd@W1+U1): h0->h1 ; cell2 (W2+U2): h1->h0 (+hist[s+1])
  for (int s = 0; s < NS - 1; ++s) {
    do_step<0>(h0, U1pp, nullptr, nullptr, 0, bC1, cst, h1, nullptr,
               lds, r0, u0, kh, wu, lr, g4, ucol, tid);
    gbar(flags, bid, ++gen);
    do_step<0>(h1, W2U2p, nullptr, nullptr, 0, bC2, cst, h0, hist + (size_t)(s + 1) * HS,
               lds, r0, u0, kh, wu, lr, g4, ucol, tid);
    if (s < NS - 2) gbar(flags, bid, ++gen);
  }
}

// ---------------- batched output projection: out[b][s][f] = hist[s][b]@Wd + bd ----------------
__global__ __launch_bounds__(256, 2) void pred_gemm(
    const unsigned short* __restrict__ H,    // [32*512][1024] bf16
    const unsigned short* __restrict__ Wdp,  // packed [128][128][8] bf16
    const float* __restrict__ bd, float* __restrict__ out)
{
  __shared__ unsigned short lds[32 * NU];
  const int tid = threadIdx.x;
  const int r0 = blockIdx.x * 32;
  for (int i = tid; i < 32 * 128; i += 256) {
    int r = i >> 7, cb = i & 127;
    uint4 v = *(const uint4*)(H + (size_t)(r0 + r) * NU + cb * 8);
    int off = r * 2048 + ((cb * 16) ^ ((r & 7) << 4));
    *(uint4*)((char*)lds + off) = v;
  }
  __syncthreads();
  const int w = tid >> 6, l = tid & 63, lr = l & 15, g4 = l >> 4;
  f32x4 acc[2][2];
#pragma unroll
  for (int a = 0; a < 2; ++a)
#pragma unroll
    for (int c = 0; c < 2; ++c) acc[a][c] = (f32x4){0.f, 0.f, 0.f, 0.f};
  const char* ldsb = (const char*)lds;
  const int arow0 = lr * 2048, arow1 = (16 + lr) * 2048, axor = (lr & 7) << 4;
  const int col0 = w * 32 + lr;
#pragma unroll 4
  for (int kc = 0; kc < 32; ++kc) {
    int kb = (kc * 64 + g4 * 16) ^ axor;
    short8 a0 = *(const short8*)(ldsb + arow0 + kb);
    short8 a1 = *(const short8*)(ldsb + arow1 + kb);
    size_t base = ((size_t)(kc * 4 + g4) * NF) * 8;
    short8 w0 = *(const short8*)(Wdp + base + (size_t)col0 * 8);
    short8 w1 = *(const short8*)(Wdp + base + (size_t)(col0 + 16) * 8);
    acc[0][0] = __builtin_amdgcn_mfma_f32_16x16x32_bf16(a0, w0, acc[0][0], 0, 0, 0);
    acc[1][0] = __builtin_amdgcn_mfma_f32_16x16x32_bf16(a1, w0, acc[1][0], 0, 0, 0);
    acc[0][1] = __builtin_amdgcn_mfma_f32_16x16x32_bf16(a0, w1, acc[0][1], 0, 0, 0);
    acc[1][1] = __builtin_amdgcn_mfma_f32_16x16x32_bf16(a1, w1, acc[1][1], 0, 0, 0);
  }
#pragma unroll
  for (int rt = 0; rt < 2; ++rt)
#pragma unroll
    for (int ct = 0; ct < 2; ++ct)
#pragma unroll
      for (int j = 0; j < 4; ++j) {
        int r = r0 + rt * 16 + g4 * 4 + j;
        int s = r >> 9, bb = r & 511;
        int f = w * 32 + ct * 16 + lr;
        out[((size_t)bb * NS + s) * NF + f] = acc[rt][ct][j] + bd[f];
      }
}

// ---------------- prep kernels ----------------
// x2 in [T][B][F] layout (contiguous per-step staging)
__global__ void prep_x(const float* __restrict__ in, const float* __restrict__ mean,
                       const float* __restrict__ var, unsigned short* __restrict__ x2) {
  int i = (blockIdx.x * 256 + threadIdx.x) * 4;
  int f = i & 127;
  int bt = i >> 7;
  int b = bt >> 6, t = bt & 63;
  float4 v = *(const float4*)(in + i);
  float vv[4] = {v.x, v.y, v.z, v.w};
  unsigned short o[4] __attribute__((aligned(8)));
#pragma unroll
  for (int j = 0; j < 4; ++j) {
    float inv = rsqrtf(var[f + j] + 1e-7f);
    float s = inv * inv;
    float m2 = mean[f + j] * (s + inv);   // double-normalization folded
    o[j] = f2bf(vv[j] * s - m2);
  }
  *(uint2*)(x2 + (((size_t)t * NB + b) << 7) + f) = *(const uint2*)o;
}

// P[(k/8)*N*8 + c*8 + k%8] = bf16(A[k][c] (+ A2[k][c]))
__global__ void prep_pack(const float* __restrict__ A, const float* __restrict__ A2,
                          unsigned short* __restrict__ P, int N) {
  int idx = blockIdx.x * 256 + threadIdx.x;
  int kg = idx / N, c = idx - kg * N;
  unsigned short o[8] __attribute__((aligned(16)));
#pragma unroll
  for (int j = 0; j < 8; ++j) {
    size_t e = (size_t)(kg * 8 + j) * N + c;
    float vv = A[e];
    if (A2) vv += A2[e];
    o[j] = f2bf(vv);
  }
  *(uint4*)(P + (size_t)idx * 8) = *(const uint4*)o;
}

// U1' = U1 + Wd@W1, packed.  Wd slice staged in LDS; m-loop unrolled.
__global__ __launch_bounds__(256) void prep_u1pp(
    const float* __restrict__ U1, const float* __restrict__ Wd,
    const float* __restrict__ W1, unsigned short* __restrict__ P) {
  __shared__ float wd[8][NF];
  const int kg = blockIdx.x >> 4;
  const int c = ((blockIdx.x & 15) << 8) + threadIdx.x;
  for (int i = threadIdx.x; i < 8 * NF; i += 256)
    wd[i >> 7][i & 127] = Wd[(size_t)(kg * 8 + (i >> 7)) * NF + (i & 127)];
  __syncthreads();
  float a[8];
#pragma unroll
  for (int j = 0; j < 8; ++j) a[j] = U1[(size_t)(kg * 8 + j) * NG + c];
#pragma unroll 8
  for (int m = 0; m < NF; ++m) {
    float w1v = W1[(size_t)m * NG + c];
#pragma unroll
    for (int j = 0; j < 8; ++j) a[j] += wd[j][m] * w1v;
  }
  unsigned short o[8] __attribute__((aligned(16)));
#pragma unroll
  for (int j = 0; j < 8; ++j) o[j] = f2bf(a[j]);
  *(uint4*)(P + (size_t)(kg * NG + c) * 8) = *(const uint4*)o;
}

__global__ void prep_wdp(const float* __restrict__ Wd, unsigned short* __restrict__ P) {
  int idx = blockIdx.x * 256 + threadIdx.x;  // kg*128 + f
  int kg = idx >> 7, f = idx & 127;
  unsigned short o[8] __attribute__((aligned(16)));
#pragma unroll
  for (int j = 0; j < 8; ++j) o[j] = f2bf(Wd[(size_t)(kg * 8 + j) * NF + f]);
  *(uint4*)(P + (size_t)idx * 8) = *(const uint4*)o;
}

// b1' = b1 + bd@W1
__global__ void prep_b1p(const float* __restrict__ b1, const float* __restrict__ bd,
                         const float* __restrict__ W1, float* __restrict__ o) {
  int c = blockIdx.x * 256 + threadIdx.x;
  float acc = b1[c];
#pragma unroll 8
  for (int m = 0; m < NF; ++m) acc += bd[m] * W1[(size_t)m * NG + c];
  o[c] = acc;
}

extern "C" void kernel_launch(void* const* d_in, const int* in_sizes, int n_in,
                              void* d_out, int out_size, void* d_ws, size_t ws_size,
                              hipStream_t stream) {
  const float* inputs = (const float*)d_in[0];
  const float* mean = (const float*)d_in[1];
  const float* var  = (const float*)d_in[2];
  const float* W1   = (const float*)d_in[3];
  const float* U1   = (const float*)d_in[4];
  const float* b1   = (const float*)d_in[5];
  const float* W2   = (const float*)d_in[6];
  const float* U2   = (const float*)d_in[7];
  const float* b2   = (const float*)d_in[8];
  const float* Wd   = (const float*)d_in[9];
  const float* bd   = (const float*)d_in[10];
  float* out = (float*)d_out;
  char* ws = (char*)d_ws;

  size_t off = 0;
  auto alloc = [&](size_t bytes) { char* p = ws + off; off += (bytes + 255) & ~255ull; return p; };
  unsigned short* h0    = (unsigned short*)alloc((size_t)NB * NU * 2);
  unsigned short* h1    = (unsigned short*)alloc((size_t)NB * NU * 2);
  unsigned short* hist  = (unsigned short*)alloc((size_t)NS * NB * NU * 2);
  unsigned short* x2    = (unsigned short*)alloc((size_t)NB * NT * NF * 2);
  unsigned short* U1p   = (unsigned short*)alloc((size_t)NU * NG * 2);
  unsigned short* U1pp  = (unsigned short*)alloc((size_t)NU * NG * 2);
  unsigned short* W2U2p = (unsigned short*)alloc((size_t)NU * NG * 2);
  unsigned short* W1p   = (unsigned short*)alloc((size_t)NF * NG * 2);
  unsigned short* Wdp   = (unsigned short*)alloc((size_t)NU * NF * 2);
  float* b1p            = (float*)alloc((size_t)NG * 4);
  unsigned* flags       = (unsigned*)alloc(2048);

  hipMemsetAsync(h0, 0, (size_t)NB * NU * 2, stream);
  hipMemsetAsync(flags, 0, 2048, stream);

  prep_x   <<<(NB * NT * NF) / 1024, 256, 0, stream>>>(inputs, mean, var, x2);
  prep_pack<<<(NU / 8) * NG / 256, 256, 0, stream>>>(U1, nullptr, U1p, NG);
  prep_u1pp<<<(NU / 8) * NG / 256, 256, 0, stream>>>(U1, Wd, W1, U1pp);
  prep_pack<<<(NU / 8) * NG / 256, 256, 0, stream>>>(W2, U2, W2U2p, NG);
  prep_pack<<<(NF / 8) * NG / 256, 256, 0, stream>>>(W1, nullptr, W1p, NG);
  prep_wdp <<<(NU / 8) * NF / 256, 256, 0, stream>>>(Wd, Wdp);
  prep_b1p <<<NG / 256, 256, 0, stream>>>(b1, bd, W1, b1p);

  // whole serial chain in one persistent kernel.
  // LDS = 64 rows x (1024+128) cols x 2B = 147456 B -> 1 block/CU -> barrier safe.
  lstm_seq<<<256, 512, 64 * (NU + NF) * 2, stream>>>(U1p, U1pp, W2U2p, W1p, x2,
                                                     b1, b1p, b2, h0, h1, hist, flags);

  // all 32 output projections in one parallel GEMM
  pred_gemm<<<(NS * NB) / 32, 256, 0, stream>>>(hist, Wdp, bd, out);
}